// Round 1
// baseline (1004.718 us; speedup 1.0000x reference)
//
#include <hip/hip_runtime.h>
#include <hip/hip_bf16.h>

#define BB 8
#define NN 16384
#define CC 128
#define MM 256
#define NS 32
#define FPS_T 1024
#define PPT (NN / FPS_T)   // 16 points per thread

// Output layout (flat f32, concatenated in return order):
//   grouped_p [B,3,M,NS]  = 196608   @ 0
//   center_p  [B,M,3]     = 6144     @ 196608
//   fj        [B,C,M,NS]  = 8388608  @ 202752
//   center_x  [B,C,M,1]   = 262144   @ 8591360
#define OFF_GP  0
#define OFF_CP  196608
#define OFF_FJ  202752
#define OFF_CX  8591360

// ---------------- FPS: one block per batch, exact numpy-f32 arithmetic ------
__global__ __launch_bounds__(FPS_T) void fps_kernel(
    const float* __restrict__ p, float* __restrict__ center_p,
    int* __restrict__ idx_out)
{
    const int b = blockIdx.x;
    const int t = threadIdx.x;
    const float* pb = p + (size_t)b * NN * 3;

    float px[PPT], py[PPT], pz[PPT], dist[PPT];
#pragma unroll
    for (int k = 0; k < PPT; ++k) {
        const int n = t + k * FPS_T;
        px[k] = pb[n * 3 + 0];
        py[k] = pb[n * 3 + 1];
        pz[k] = pb[n * 3 + 2];
        dist[k] = 1e10f;
    }

    __shared__ float s_wv[16];
    __shared__ int   s_wn[16];
    __shared__ float s_cur[3];

    if (t == 0) {
        idx_out[b * MM + 0] = 0;
        const float a = pb[0], b2 = pb[1], c2 = pb[2];
        center_p[(b * MM + 0) * 3 + 0] = a;
        center_p[(b * MM + 0) * 3 + 1] = b2;
        center_p[(b * MM + 0) * 3 + 2] = c2;
        s_cur[0] = a; s_cur[1] = b2; s_cur[2] = c2;
    }
    __syncthreads();

    for (int i = 1; i < MM; ++i) {
        const float cx = s_cur[0], cy = s_cur[1], cz = s_cur[2];
        float bv = -1.0f;
        int   bn = 0x7fffffff;
#pragma unroll
        for (int k = 0; k < PPT; ++k) {
            // exact numpy order: ((dx*dx + dy*dy) + dz*dz), no FMA contraction
            const float dx = __fsub_rn(px[k], cx);
            const float dy = __fsub_rn(py[k], cy);
            const float dz = __fsub_rn(pz[k], cz);
            const float d = __fadd_rn(
                __fadd_rn(__fmul_rn(dx, dx), __fmul_rn(dy, dy)),
                __fmul_rn(dz, dz));
            const float nd = fminf(dist[k], d);
            dist[k] = nd;
            // strict > keeps smallest k (per-thread indices ascend with k)
            if (nd > bv) { bv = nd; bn = t + k * FPS_T; }
        }
        // wave-level argmax with first-occurrence (smaller index) tie-break
#pragma unroll
        for (int off = 32; off > 0; off >>= 1) {
            const float ov = __shfl_down(bv, off);
            const int   on = __shfl_down(bn, off);
            if (ov > bv || (ov == bv && on < bn)) { bv = ov; bn = on; }
        }
        if ((t & 63) == 0) { s_wv[t >> 6] = bv; s_wn[t >> 6] = bn; }
        __syncthreads();
        if (t == 0) {
            float fv = s_wv[0]; int fn = s_wn[0];
#pragma unroll
            for (int w = 1; w < 16; ++w) {
                if (s_wv[w] > fv || (s_wv[w] == fv && s_wn[w] < fn)) {
                    fv = s_wv[w]; fn = s_wn[w];
                }
            }
            const float* cp = pb + (size_t)fn * 3;
            const float a = cp[0], b2 = cp[1], c2 = cp[2];
            s_cur[0] = a; s_cur[1] = b2; s_cur[2] = c2;
            idx_out[b * MM + i] = fn;
            float* o = center_p + (size_t)(b * MM + i) * 3;
            o[0] = a; o[1] = b2; o[2] = c2;
        }
        __syncthreads();
    }
}

// ---------------- Ball query: one wave per center ---------------------------
__global__ __launch_bounds__(64) void ballq_kernel(
    const float* __restrict__ p, const int* __restrict__ idx,
    int* __restrict__ nidx, float* __restrict__ grouped_p)
{
    const int bm = blockIdx.x;
    const int b = bm >> 8;
    const int m = bm & 255;
    const int lane = threadIdx.x;
    const float* pb = p + (size_t)b * NN * 3;

    const int cidx = idx[bm];
    const float cx = pb[cidx * 3 + 0];
    const float cy = pb[cidx * 3 + 1];
    const float cz = pb[cidx * 3 + 2];

    // r2 must be f32(0.01) == 0x3C23D70A; 0.1f*0.1f rounds one ULP higher.
    const float R2 = 0.01f;

    __shared__ int lidx[NS];

    int found = 0;
    for (int chunk = 0; chunk < NN / 64 && found < NS; ++chunk) {
        const int n = chunk * 64 + lane;
        const float dx = __fsub_rn(pb[n * 3 + 0], cx);
        const float dy = __fsub_rn(pb[n * 3 + 1], cy);
        const float dz = __fsub_rn(pb[n * 3 + 2], cz);
        const float d2 = __fadd_rn(
            __fadd_rn(__fmul_rn(dx, dx), __fmul_rn(dy, dy)),
            __fmul_rn(dz, dz));
        const bool within = d2 < R2;
        const unsigned long long mask = __ballot(within);
        const int prefix = __popcll(mask & ((1ull << lane) - 1ull));
        const int slot = found + prefix;
        if (within && slot < NS) lidx[slot] = n;
        found += (int)__popcll(mask);
    }
    __syncthreads();

    const int nfound = found < NS ? found : NS;
    if (lane < NS) {
        const int s = lane;
        const int n = (s < nfound) ? lidx[s] : lidx[0];
        nidx[bm * NS + s] = n;
        const float gx = __fsub_rn(pb[n * 3 + 0], cx);
        const float gy = __fsub_rn(pb[n * 3 + 1], cy);
        const float gz = __fsub_rn(pb[n * 3 + 2], cz);
        grouped_p[(((size_t)b * 3 + 0) * MM + m) * NS + s] = gx;
        grouped_p[(((size_t)b * 3 + 1) * MM + m) * NS + s] = gy;
        grouped_p[(((size_t)b * 3 + 2) * MM + m) * NS + s] = gz;
    }
}

// ---------------- fj gather: one block per (b,m) ----------------------------
__global__ __launch_bounds__(256) void fj_kernel(
    const float* __restrict__ x, const int* __restrict__ nidx,
    float* __restrict__ fj)
{
    const int bm = blockIdx.x;
    const int b = bm >> 8;
    const int m = bm & 255;

    __shared__ int lidx[NS];
    if (threadIdx.x < NS) lidx[threadIdx.x] = nidx[bm * NS + threadIdx.x];
    __syncthreads();

    const int s  = threadIdx.x & 31;
    const int c0 = threadIdx.x >> 5;   // 0..7
    const int n = lidx[s];
    const float* xb = x + (size_t)b * CC * NN;
    float* ob = fj + (size_t)b * CC * MM * NS + (size_t)m * NS + s;

#pragma unroll
    for (int c = c0; c < CC; c += 8) {
        ob[(size_t)c * MM * NS] = xb[(size_t)c * NN + n];
    }
}

// ---------------- center_x gather: one block per (b,c) ----------------------
__global__ __launch_bounds__(256) void cx_kernel(
    const float* __restrict__ x, const int* __restrict__ idx,
    float* __restrict__ center_x)
{
    const int bc = blockIdx.x;
    const int b = bc >> 7;
    const int m = threadIdx.x;
    const int n = idx[b * MM + m];
    center_x[(size_t)bc * MM + m] = x[(size_t)bc * NN + n];
}

extern "C" void kernel_launch(void* const* d_in, const int* in_sizes, int n_in,
                              void* d_out, int out_size, void* d_ws, size_t ws_size,
                              hipStream_t stream) {
    const float* p = (const float*)d_in[0];   // [8,16384,3]
    const float* x = (const float*)d_in[1];   // [8,128,16384]
    float* out = (float*)d_out;

    float* grouped_p = out + OFF_GP;
    float* center_p  = out + OFF_CP;
    float* fj        = out + OFF_FJ;
    float* center_x  = out + OFF_CX;

    int* idx  = (int*)d_ws;                   // [8,256]
    int* nidx = idx + BB * MM;                // [8,256,32]

    fps_kernel<<<BB, FPS_T, 0, stream>>>(p, center_p, idx);
    ballq_kernel<<<BB * MM, 64, 0, stream>>>(p, idx, nidx, grouped_p);
    fj_kernel<<<BB * MM, 256, 0, stream>>>(x, nidx, fj);
    cx_kernel<<<BB * CC, 256, 0, stream>>>(x, idx, center_x);
}

// Round 2
// 712.989 us; speedup vs baseline: 1.4092x; 1.4092x over previous
//
#include <hip/hip_runtime.h>
#include <hip/hip_bf16.h>

#define BB 8
#define NN 16384
#define CC 128
#define MM 256
#define NS 32
#define FPS_T 1024
#define PPT (NN / FPS_T)   // 16 points per thread

// Output layout (flat f32, concatenated in return order):
//   grouped_p [B,3,M,NS]  = 196608   @ 0
//   center_p  [B,M,3]     = 6144     @ 196608
//   fj        [B,C,M,NS]  = 8388608  @ 202752
//   center_x  [B,C,M,1]   = 262144   @ 8591360
#define OFF_GP  0
#define OFF_CP  196608
#define OFF_FJ  202752
#define OFF_CX  8591360

// ---------------- FPS: one block per batch ----------------------------------
// Exact numpy-f32 arithmetic: __f*_rn intrinsics block FMA contraction;
// distances >= 0 so float bit-pattern order == value order; key = bits<<32|~n
// gives argmax with smallest-index tiebreak as a single u64 max.
__global__ __launch_bounds__(FPS_T) void fps_kernel(
    const float* __restrict__ p, int* __restrict__ idx_out)
{
    const int b = blockIdx.x;
    const int t = threadIdx.x;
    const float* pb = p + (size_t)b * NN * 3;

    float px[PPT], py[PPT], pz[PPT], dist[PPT];
#pragma unroll
    for (int k = 0; k < PPT; ++k) {
        const int n = t + k * FPS_T;
        px[k] = pb[n * 3 + 0];
        py[k] = pb[n * 3 + 1];
        pz[k] = pb[n * 3 + 2];
        dist[k] = 1e10f;
    }

    // double-buffered wave candidates -> one barrier per iteration
    __shared__ unsigned long long s_key[2][16];

    // current center in registers on every thread
    float cx = pb[0], cy = pb[1], cz = pb[2];
    if (t == 0) idx_out[b * MM + 0] = 0;

    for (int i = 1; i < MM; ++i) {
        float bv = -1.0f;
        int   bn = 0;
#pragma unroll
        for (int k = 0; k < PPT; ++k) {
            // exact numpy order: ((dx*dx + dy*dy) + dz*dz)
            const float dx = __fsub_rn(px[k], cx);
            const float dy = __fsub_rn(py[k], cy);
            const float dz = __fsub_rn(pz[k], cz);
            const float d = __fadd_rn(
                __fadd_rn(__fmul_rn(dx, dx), __fmul_rn(dy, dy)),
                __fmul_rn(dz, dz));
            const float nd = fminf(dist[k], d);
            dist[k] = nd;
            // strict > keeps smallest k (per-thread indices ascend with k)
            if (nd > bv) { bv = nd; bn = t + k * FPS_T; }
        }
        unsigned long long key =
            ((unsigned long long)__float_as_uint(bv) << 32) |
            (unsigned int)(~bn);
        // 64-lane butterfly: every lane ends with the wave max key
#pragma unroll
        for (int off = 32; off > 0; off >>= 1) {
            const unsigned long long ok = __shfl_xor(key, off);
            if (ok > key) key = ok;
        }
        const int buf = i & 1;
        if ((t & 63) == 0) s_key[buf][t >> 6] = key;
        __syncthreads();
        // every wave redundantly reduces the 16 candidates (broadcast reads)
        unsigned long long fk = s_key[buf][0];
#pragma unroll
        for (int w = 1; w < 16; ++w) {
            const unsigned long long k2 = s_key[buf][w];
            if (k2 > fk) fk = k2;
        }
        const int fn = ~((unsigned int)fk);
        // uniform broadcast load of the new center (L2-resident)
        cx = pb[fn * 3 + 0];
        cy = pb[fn * 3 + 1];
        cz = pb[fn * 3 + 2];
        if (t == 0) idx_out[b * MM + i] = fn;
        // no second barrier: next iter writes s_key[buf^1]; writes to
        // s_key[buf] recur only after the NEXT barrier, which orders them
        // after every wave's reads above.
    }
}

// ---------------- Ball query: one wave per center ---------------------------
__global__ __launch_bounds__(64) void ballq_kernel(
    const float* __restrict__ p, const int* __restrict__ idx,
    int* __restrict__ nidx, float* __restrict__ grouped_p,
    float* __restrict__ center_p)
{
    const int bm = blockIdx.x;
    const int b = bm >> 8;
    const int m = bm & 255;
    const int lane = threadIdx.x;
    const float* pb = p + (size_t)b * NN * 3;

    const int cidx = idx[bm];
    const float cx = pb[cidx * 3 + 0];
    const float cy = pb[cidx * 3 + 1];
    const float cz = pb[cidx * 3 + 2];

    if (lane < 3) {
        center_p[bm * 3 + lane] = (lane == 0) ? cx : (lane == 1) ? cy : cz;
    }

    // r2 must be f32(0.01) == 0x3C23D70A; 0.1f*0.1f rounds one ULP higher.
    const float R2 = 0.01f;

    __shared__ int lidx[NS];

    int found = 0;
    for (int chunk = 0; chunk < NN / 64 && found < NS; ++chunk) {
        const int n = chunk * 64 + lane;
        const float dx = __fsub_rn(pb[n * 3 + 0], cx);
        const float dy = __fsub_rn(pb[n * 3 + 1], cy);
        const float dz = __fsub_rn(pb[n * 3 + 2], cz);
        const float d2 = __fadd_rn(
            __fadd_rn(__fmul_rn(dx, dx), __fmul_rn(dy, dy)),
            __fmul_rn(dz, dz));
        const bool within = d2 < R2;
        const unsigned long long mask = __ballot(within);
        const int prefix = __popcll(mask & ((1ull << lane) - 1ull));
        const int slot = found + prefix;
        if (within && slot < NS) lidx[slot] = n;
        found += (int)__popcll(mask);
    }
    __syncthreads();

    const int nfound = found < NS ? found : NS;
    if (lane < NS) {
        const int s = lane;
        const int n = (s < nfound) ? lidx[s] : lidx[0];
        nidx[bm * NS + s] = n;
        const float gx = __fsub_rn(pb[n * 3 + 0], cx);
        const float gy = __fsub_rn(pb[n * 3 + 1], cy);
        const float gz = __fsub_rn(pb[n * 3 + 2], cz);
        grouped_p[(((size_t)b * 3 + 0) * MM + m) * NS + s] = gx;
        grouped_p[(((size_t)b * 3 + 1) * MM + m) * NS + s] = gy;
        grouped_p[(((size_t)b * 3 + 2) * MM + m) * NS + s] = gz;
    }
}

// ---------------- fj gather: one block per (b,m) ----------------------------
__global__ __launch_bounds__(256) void fj_kernel(
    const float* __restrict__ x, const int* __restrict__ nidx,
    float* __restrict__ fj)
{
    const int bm = blockIdx.x;
    const int b = bm >> 8;
    const int m = bm & 255;

    __shared__ int lidx[NS];
    if (threadIdx.x < NS) lidx[threadIdx.x] = nidx[bm * NS + threadIdx.x];
    __syncthreads();

    const int s  = threadIdx.x & 31;
    const int c0 = threadIdx.x >> 5;   // 0..7
    const int n = lidx[s];
    const float* xb = x + (size_t)b * CC * NN;
    float* ob = fj + (size_t)b * CC * MM * NS + (size_t)m * NS + s;

#pragma unroll
    for (int c = c0; c < CC; c += 8) {
        ob[(size_t)c * MM * NS] = xb[(size_t)c * NN + n];
    }
}

// ---------------- center_x gather: one block per (b,c) ----------------------
__global__ __launch_bounds__(256) void cx_kernel(
    const float* __restrict__ x, const int* __restrict__ idx,
    float* __restrict__ center_x)
{
    const int bc = blockIdx.x;
    const int b = bc >> 7;
    const int m = threadIdx.x;
    const int n = idx[b * MM + m];
    center_x[(size_t)bc * MM + m] = x[(size_t)bc * NN + n];
}

extern "C" void kernel_launch(void* const* d_in, const int* in_sizes, int n_in,
                              void* d_out, int out_size, void* d_ws, size_t ws_size,
                              hipStream_t stream) {
    const float* p = (const float*)d_in[0];   // [8,16384,3]
    const float* x = (const float*)d_in[1];   // [8,128,16384]
    float* out = (float*)d_out;

    float* grouped_p = out + OFF_GP;
    float* center_p  = out + OFF_CP;
    float* fj        = out + OFF_FJ;
    float* center_x  = out + OFF_CX;

    int* idx  = (int*)d_ws;                   // [8,256]
    int* nidx = idx + BB * MM;                // [8,256,32]

    fps_kernel<<<BB, FPS_T, 0, stream>>>(p, idx);
    ballq_kernel<<<BB * MM, 64, 0, stream>>>(p, idx, nidx, grouped_p, center_p);
    fj_kernel<<<BB * MM, 256, 0, stream>>>(x, nidx, fj);
    cx_kernel<<<BB * CC, 256, 0, stream>>>(x, idx, center_x);
}

// Round 3
// 677.933 us; speedup vs baseline: 1.4820x; 1.0517x over previous
//
#include <hip/hip_runtime.h>
#include <hip/hip_bf16.h>

#define BB 8
#define NN 16384
#define CC 128
#define MM 256
#define NS 32
#define FPS_T 1024
#define PPT (NN / FPS_T)   // 16 points per thread

// Output layout (flat f32, concatenated in return order):
//   grouped_p [B,3,M,NS]  = 196608   @ 0
//   center_p  [B,M,3]     = 6144     @ 196608
//   fj        [B,C,M,NS]  = 8388608  @ 202752
//   center_x  [B,C,M,1]   = 262144   @ 8591360
#define OFF_GP  0
#define OFF_CP  196608
#define OFF_FJ  202752
#define OFF_CX  8591360

// ---------------- FPS: one block per batch ----------------------------------
// Exact numpy-f32 arithmetic: __f*_rn intrinsics block FMA contraction;
// distances >= 0 so float bit-pattern order == value order; key = bits<<32|~n
// gives argmax with smallest-index tiebreak as a single u64 max.
// launch_bounds(1024,4): 4 waves/EU -> VGPR cap 128, enough to keep
// px/py/pz/dist (64 regs) register-resident. Without it the compiler
// targeted <=64 VGPRs and re-streamed points from L2 every iteration
// (R1: VGPR_Count=48, 477us).
__global__ __launch_bounds__(FPS_T, 4) void fps_kernel(
    const float* __restrict__ p, int* __restrict__ idx_out)
{
    const int b = blockIdx.x;
    const int t = threadIdx.x;
    const float* pb = p + (size_t)b * NN * 3;

    float px[PPT], py[PPT], pz[PPT], dist[PPT];
#pragma unroll
    for (int k = 0; k < PPT; ++k) {
        const int n = t + k * FPS_T;
        px[k] = pb[n * 3 + 0];
        py[k] = pb[n * 3 + 1];
        pz[k] = pb[n * 3 + 2];
        dist[k] = 1e10f;
    }

    // double-buffered wave candidates -> one barrier per iteration
    __shared__ unsigned long long s_key[2][16];

    // current center in registers on every thread
    float cx = pb[0], cy = pb[1], cz = pb[2];
    if (t == 0) idx_out[b * MM + 0] = 0;

    for (int i = 1; i < MM; ++i) {
        float bv = -1.0f;
        int   bn = 0;
#pragma unroll
        for (int k = 0; k < PPT; ++k) {
            // exact numpy order: ((dx*dx + dy*dy) + dz*dz)
            const float dx = __fsub_rn(px[k], cx);
            const float dy = __fsub_rn(py[k], cy);
            const float dz = __fsub_rn(pz[k], cz);
            const float d = __fadd_rn(
                __fadd_rn(__fmul_rn(dx, dx), __fmul_rn(dy, dy)),
                __fmul_rn(dz, dz));
            const float nd = fminf(dist[k], d);
            dist[k] = nd;
            // strict > keeps smallest k (per-thread indices ascend with k)
            if (nd > bv) { bv = nd; bn = t + k * FPS_T; }
        }
        unsigned long long key =
            ((unsigned long long)__float_as_uint(bv) << 32) |
            (unsigned int)(~bn);
        // 64-lane butterfly: every lane ends with the wave max key
#pragma unroll
        for (int off = 32; off > 0; off >>= 1) {
            const unsigned long long ok = __shfl_xor(key, off);
            if (ok > key) key = ok;
        }
        const int buf = i & 1;
        if ((t & 63) == 0) s_key[buf][t >> 6] = key;
        __syncthreads();
        // every wave redundantly reduces the 16 candidates (broadcast reads)
        unsigned long long fk = s_key[buf][0];
#pragma unroll
        for (int w = 1; w < 16; ++w) {
            const unsigned long long k2 = s_key[buf][w];
            if (k2 > fk) fk = k2;
        }
        const int fn = ~((unsigned int)fk);
        // uniform broadcast load of the new center (L2-resident)
        cx = pb[fn * 3 + 0];
        cy = pb[fn * 3 + 1];
        cz = pb[fn * 3 + 2];
        if (t == 0) idx_out[b * MM + i] = fn;
        // no second barrier: next iter writes s_key[buf^1]; writes to
        // s_key[buf] recur only after the NEXT barrier, which orders them
        // after every wave's reads above.
    }
}

// ---------------- Ball query: one wave per center, 128 pts/iter -------------
__global__ __launch_bounds__(64) void ballq_kernel(
    const float* __restrict__ p, const int* __restrict__ idx,
    int* __restrict__ nidx, float* __restrict__ grouped_p,
    float* __restrict__ center_p)
{
    const int bm = blockIdx.x;
    const int b = bm >> 8;
    const int m = bm & 255;
    const int lane = threadIdx.x;
    const float* pb = p + (size_t)b * NN * 3;

    const int cidx = idx[bm];
    const float cx = pb[cidx * 3 + 0];
    const float cy = pb[cidx * 3 + 1];
    const float cz = pb[cidx * 3 + 2];

    if (lane < 3) {
        center_p[bm * 3 + lane] = (lane == 0) ? cx : (lane == 1) ? cy : cz;
    }

    // r2 must be f32(0.01) == 0x3C23D70A; 0.1f*0.1f rounds one ULP higher.
    const float R2 = 0.01f;

    __shared__ int lidx[NS];

    int found = 0;
    for (int base = 0; base < NN && found < NS; base += 128) {
        const int n0 = base + lane;
        const int n1 = base + 64 + lane;
        const float dx0 = __fsub_rn(pb[n0 * 3 + 0], cx);
        const float dy0 = __fsub_rn(pb[n0 * 3 + 1], cy);
        const float dz0 = __fsub_rn(pb[n0 * 3 + 2], cz);
        const float d20 = __fadd_rn(
            __fadd_rn(__fmul_rn(dx0, dx0), __fmul_rn(dy0, dy0)),
            __fmul_rn(dz0, dz0));
        const float dx1 = __fsub_rn(pb[n1 * 3 + 0], cx);
        const float dy1 = __fsub_rn(pb[n1 * 3 + 1], cy);
        const float dz1 = __fsub_rn(pb[n1 * 3 + 2], cz);
        const float d21 = __fadd_rn(
            __fadd_rn(__fmul_rn(dx1, dx1), __fmul_rn(dy1, dy1)),
            __fmul_rn(dz1, dz1));
        const bool w0 = d20 < R2;
        const bool w1 = d21 < R2;
        const unsigned long long m0 = __ballot(w0);
        const unsigned long long m1 = __ballot(w1);
        const int pc0 = (int)__popcll(m0);
        const unsigned long long below = (1ull << lane) - 1ull;
        const int slot0 = found + __popcll(m0 & below);
        const int slot1 = found + pc0 + __popcll(m1 & below);
        if (w0 && slot0 < NS) lidx[slot0] = n0;
        if (w1 && slot1 < NS) lidx[slot1] = n1;
        found += pc0 + (int)__popcll(m1);
    }
    __syncthreads();

    const int nfound = found < NS ? found : NS;
    if (lane < NS) {
        const int s = lane;
        const int n = (s < nfound) ? lidx[s] : lidx[0];
        nidx[bm * NS + s] = n;
        const float gx = __fsub_rn(pb[n * 3 + 0], cx);
        const float gy = __fsub_rn(pb[n * 3 + 1], cy);
        const float gz = __fsub_rn(pb[n * 3 + 2], cz);
        grouped_p[(((size_t)b * 3 + 0) * MM + m) * NS + s] = gx;
        grouped_p[(((size_t)b * 3 + 1) * MM + m) * NS + s] = gy;
        grouped_p[(((size_t)b * 3 + 2) * MM + m) * NS + s] = gz;
    }
}

// ---------------- fj gather: one block per (b,m) ----------------------------
__global__ __launch_bounds__(256) void fj_kernel(
    const float* __restrict__ x, const int* __restrict__ nidx,
    float* __restrict__ fj)
{
    const int bm = blockIdx.x;
    const int b = bm >> 8;
    const int m = bm & 255;

    __shared__ int lidx[NS];
    if (threadIdx.x < NS) lidx[threadIdx.x] = nidx[bm * NS + threadIdx.x];
    __syncthreads();

    const int s  = threadIdx.x & 31;
    const int c0 = threadIdx.x >> 5;   // 0..7
    const int n = lidx[s];
    const float* xb = x + (size_t)b * CC * NN;
    float* ob = fj + (size_t)b * CC * MM * NS + (size_t)m * NS + s;

#pragma unroll
    for (int c = c0; c < CC; c += 8) {
        ob[(size_t)c * MM * NS] = xb[(size_t)c * NN + n];
    }
}

// ---------------- center_x gather: one block per (b,c) ----------------------
__global__ __launch_bounds__(256) void cx_kernel(
    const float* __restrict__ x, const int* __restrict__ idx,
    float* __restrict__ center_x)
{
    const int bc = blockIdx.x;
    const int b = bc >> 7;
    const int m = threadIdx.x;
    const int n = idx[b * MM + m];
    center_x[(size_t)bc * MM + m] = x[(size_t)bc * NN + n];
}

extern "C" void kernel_launch(void* const* d_in, const int* in_sizes, int n_in,
                              void* d_out, int out_size, void* d_ws, size_t ws_size,
                              hipStream_t stream) {
    const float* p = (const float*)d_in[0];   // [8,16384,3]
    const float* x = (const float*)d_in[1];   // [8,128,16384]
    float* out = (float*)d_out;

    float* grouped_p = out + OFF_GP;
    float* center_p  = out + OFF_CP;
    float* fj        = out + OFF_FJ;
    float* center_x  = out + OFF_CX;

    int* idx  = (int*)d_ws;                   // [8,256]
    int* nidx = idx + BB * MM;                // [8,256,32]

    fps_kernel<<<BB, FPS_T, 0, stream>>>(p, idx);
    ballq_kernel<<<BB * MM, 64, 0, stream>>>(p, idx, nidx, grouped_p, center_p);
    fj_kernel<<<BB * MM, 256, 0, stream>>>(x, nidx, fj);
    cx_kernel<<<BB * CC, 256, 0, stream>>>(x, idx, center_x);
}

// Round 4
// 673.121 us; speedup vs baseline: 1.4926x; 1.0071x over previous
//
#include <hip/hip_runtime.h>
#include <hip/hip_bf16.h>

#define BB 8
#define NN 16384
#define CC 128
#define MM 256
#define NS 32
#define FPS_T 1024
#define PPT (NN / FPS_T)   // 16 points per thread

// Output layout (flat f32, concatenated in return order):
//   grouped_p [B,3,M,NS]  = 196608   @ 0
//   center_p  [B,M,3]     = 6144     @ 196608
//   fj        [B,C,M,NS]  = 8388608  @ 202752
//   center_x  [B,C,M,1]   = 262144   @ 8591360
#define OFF_GP  0
#define OFF_CP  196608
#define OFF_FJ  202752
#define OFF_CX  8591360

// ---------------- FPS: one block per batch ----------------------------------
// Exact numpy-f32 arithmetic: __f*_rn intrinsics block FMA contraction;
// distances >= 0 so float bit-pattern order == value order; key = bits<<32|~n
// gives argmax with smallest-index tiebreak as a single u64 max.
//
// R2 lesson: launch_bounds(1024,4) caps VGPR at 128 but the allocator still
// chose 48, SINKING the loop-invariant point loads into the 255-iter loop
// (L2 re-stream every iteration). Fix: asm-pin the loaded values — the asm
// output is not rematerializable, forcing true register residency (~96 VGPR).
__global__ __launch_bounds__(FPS_T, 4) void fps_kernel(
    const float* __restrict__ p, int* __restrict__ idx_out)
{
    const int b = blockIdx.x;
    const int t = threadIdx.x;
    const float* pb = p + (size_t)b * NN * 3;

    float px[PPT], py[PPT], pz[PPT], dist[PPT];
#pragma unroll
    for (int k = 0; k < PPT; ++k) {
        const int n = t + k * FPS_T;
        px[k] = pb[n * 3 + 0];
        py[k] = pb[n * 3 + 1];
        pz[k] = pb[n * 3 + 2];
        dist[k] = 1e10f;
    }
    // Pin: forbid the register allocator from sinking/rematerializing these
    // loads inside the i-loop. Values become opaque asm results.
#pragma unroll
    for (int k = 0; k < PPT; ++k) {
        asm volatile("" : "+v"(px[k]), "+v"(py[k]), "+v"(pz[k]));
    }

    // double-buffered wave candidates -> one barrier per iteration
    __shared__ unsigned long long s_key[2][16];

    // current center in registers on every thread
    float cx = pb[0], cy = pb[1], cz = pb[2];
    if (t == 0) idx_out[b * MM + 0] = 0;

    for (int i = 1; i < MM; ++i) {
        float bv = -1.0f;
#pragma unroll
        for (int k = 0; k < PPT; ++k) {
            // exact numpy order: ((dx*dx + dy*dy) + dz*dz)
            const float dx = __fsub_rn(px[k], cx);
            const float dy = __fsub_rn(py[k], cy);
            const float dz = __fsub_rn(pz[k], cz);
            const float d = __fadd_rn(
                __fadd_rn(__fmul_rn(dx, dx), __fmul_rn(dy, dy)),
                __fmul_rn(dz, dz));
            const float nd = fminf(dist[k], d);
            dist[k] = nd;
            bv = fmaxf(bv, nd);
        }
        // post-pass argmax: descending k, == match -> smallest k wins,
        // identical selection to the in-loop strict-> version.
        int bn = 0;
#pragma unroll
        for (int k = PPT - 1; k >= 0; --k) {
            if (dist[k] == bv) bn = t + k * FPS_T;
        }
        unsigned long long key =
            ((unsigned long long)__float_as_uint(bv) << 32) |
            (unsigned int)(~bn);
        // 64-lane butterfly: every lane ends with the wave max key
#pragma unroll
        for (int off = 32; off > 0; off >>= 1) {
            const unsigned long long ok = __shfl_xor(key, off);
            if (ok > key) key = ok;
        }
        const int buf = i & 1;
        if ((t & 63) == 0) s_key[buf][t >> 6] = key;
        __syncthreads();
        // every wave redundantly reduces the 16 candidates (broadcast reads)
        unsigned long long fk = s_key[buf][0];
#pragma unroll
        for (int w = 1; w < 16; ++w) {
            const unsigned long long k2 = s_key[buf][w];
            if (k2 > fk) fk = k2;
        }
        const int fn = ~((unsigned int)fk);
        // uniform broadcast load of the new center (L2-resident)
        cx = pb[fn * 3 + 0];
        cy = pb[fn * 3 + 1];
        cz = pb[fn * 3 + 2];
        if (t == 0) idx_out[b * MM + i] = fn;
        // no second barrier: next iter writes s_key[buf^1]; writes to
        // s_key[buf] recur only after the NEXT barrier, which orders them
        // after every wave's reads above.
    }
}

// ---------------- Ball query: one wave per center, 128 pts/iter -------------
__global__ __launch_bounds__(64) void ballq_kernel(
    const float* __restrict__ p, const int* __restrict__ idx,
    int* __restrict__ nidx, float* __restrict__ grouped_p,
    float* __restrict__ center_p)
{
    const int bm = blockIdx.x;
    const int b = bm >> 8;
    const int m = bm & 255;
    const int lane = threadIdx.x;
    const float* pb = p + (size_t)b * NN * 3;

    const int cidx = idx[bm];
    const float cx = pb[cidx * 3 + 0];
    const float cy = pb[cidx * 3 + 1];
    const float cz = pb[cidx * 3 + 2];

    if (lane < 3) {
        center_p[bm * 3 + lane] = (lane == 0) ? cx : (lane == 1) ? cy : cz;
    }

    // r2 must be f32(0.01) == 0x3C23D70A; 0.1f*0.1f rounds one ULP higher.
    const float R2 = 0.01f;

    __shared__ int lidx[NS];

    int found = 0;
    for (int base = 0; base < NN && found < NS; base += 128) {
        const int n0 = base + lane;
        const int n1 = base + 64 + lane;
        const float dx0 = __fsub_rn(pb[n0 * 3 + 0], cx);
        const float dy0 = __fsub_rn(pb[n0 * 3 + 1], cy);
        const float dz0 = __fsub_rn(pb[n0 * 3 + 2], cz);
        const float d20 = __fadd_rn(
            __fadd_rn(__fmul_rn(dx0, dx0), __fmul_rn(dy0, dy0)),
            __fmul_rn(dz0, dz0));
        const float dx1 = __fsub_rn(pb[n1 * 3 + 0], cx);
        const float dy1 = __fsub_rn(pb[n1 * 3 + 1], cy);
        const float dz1 = __fsub_rn(pb[n1 * 3 + 2], cz);
        const float d21 = __fadd_rn(
            __fadd_rn(__fmul_rn(dx1, dx1), __fmul_rn(dy1, dy1)),
            __fmul_rn(dz1, dz1));
        const bool w0 = d20 < R2;
        const bool w1 = d21 < R2;
        const unsigned long long m0 = __ballot(w0);
        const unsigned long long m1 = __ballot(w1);
        const int pc0 = (int)__popcll(m0);
        const unsigned long long below = (1ull << lane) - 1ull;
        const int slot0 = found + __popcll(m0 & below);
        const int slot1 = found + pc0 + __popcll(m1 & below);
        if (w0 && slot0 < NS) lidx[slot0] = n0;
        if (w1 && slot1 < NS) lidx[slot1] = n1;
        found += pc0 + (int)__popcll(m1);
    }
    __syncthreads();

    const int nfound = found < NS ? found : NS;
    if (lane < NS) {
        const int s = lane;
        const int n = (s < nfound) ? lidx[s] : lidx[0];
        nidx[bm * NS + s] = n;
        const float gx = __fsub_rn(pb[n * 3 + 0], cx);
        const float gy = __fsub_rn(pb[n * 3 + 1], cy);
        const float gz = __fsub_rn(pb[n * 3 + 2], cz);
        grouped_p[(((size_t)b * 3 + 0) * MM + m) * NS + s] = gx;
        grouped_p[(((size_t)b * 3 + 1) * MM + m) * NS + s] = gy;
        grouped_p[(((size_t)b * 3 + 2) * MM + m) * NS + s] = gz;
    }
}

// ---------------- fj gather: one block per (b,m) ----------------------------
__global__ __launch_bounds__(256) void fj_kernel(
    const float* __restrict__ x, const int* __restrict__ nidx,
    float* __restrict__ fj)
{
    const int bm = blockIdx.x;
    const int b = bm >> 8;
    const int m = bm & 255;

    __shared__ int lidx[NS];
    if (threadIdx.x < NS) lidx[threadIdx.x] = nidx[bm * NS + threadIdx.x];
    __syncthreads();

    const int s  = threadIdx.x & 31;
    const int c0 = threadIdx.x >> 5;   // 0..7
    const int n = lidx[s];
    const float* xb = x + (size_t)b * CC * NN;
    float* ob = fj + (size_t)b * CC * MM * NS + (size_t)m * NS + s;

#pragma unroll
    for (int c = c0; c < CC; c += 8) {
        ob[(size_t)c * MM * NS] = xb[(size_t)c * NN + n];
    }
}

// ---------------- center_x gather: one block per (b,c) ----------------------
__global__ __launch_bounds__(256) void cx_kernel(
    const float* __restrict__ x, const int* __restrict__ idx,
    float* __restrict__ center_x)
{
    const int bc = blockIdx.x;
    const int b = bc >> 7;
    const int m = threadIdx.x;
    const int n = idx[b * MM + m];
    center_x[(size_t)bc * MM + m] = x[(size_t)bc * NN + n];
}

extern "C" void kernel_launch(void* const* d_in, const int* in_sizes, int n_in,
                              void* d_out, int out_size, void* d_ws, size_t ws_size,
                              hipStream_t stream) {
    const float* p = (const float*)d_in[0];   // [8,16384,3]
    const float* x = (const float*)d_in[1];   // [8,128,16384]
    float* out = (float*)d_out;

    float* grouped_p = out + OFF_GP;
    float* center_p  = out + OFF_CP;
    float* fj        = out + OFF_FJ;
    float* center_x  = out + OFF_CX;

    int* idx  = (int*)d_ws;                   // [8,256]
    int* nidx = idx + BB * MM;                // [8,256,32]

    fps_kernel<<<BB, FPS_T, 0, stream>>>(p, idx);
    ballq_kernel<<<BB * MM, 64, 0, stream>>>(p, idx, nidx, grouped_p, center_p);
    fj_kernel<<<BB * MM, 256, 0, stream>>>(x, nidx, fj);
    cx_kernel<<<BB * CC, 256, 0, stream>>>(x, idx, center_x);
}

// Round 5
// 643.696 us; speedup vs baseline: 1.5609x; 1.0457x over previous
//
#include <hip/hip_runtime.h>
#include <hip/hip_bf16.h>

#define BB 8
#define NN 16384
#define CC 128
#define MM 256
#define NS 32
#define FPS_T 1024
#define PPT (NN / FPS_T)   // 16 points per thread

// Output layout (flat f32, concatenated in return order):
//   grouped_p [B,3,M,NS]  = 196608   @ 0
//   center_p  [B,M,3]     = 6144     @ 196608
//   fj        [B,C,M,NS]  = 8388608  @ 202752
//   center_x  [B,C,M,1]   = 262144   @ 8591360
#define OFF_GP  0
#define OFF_CP  196608
#define OFF_FJ  202752
#define OFF_CX  8591360

// ---------------- FPS: one block per batch ----------------------------------
// Exact numpy-f32 arithmetic: __f*_rn intrinsics block FMA contraction;
// distances >= 0 so float bit-pattern order == value order; key = bits<<32|~n
// gives argmax with smallest-index tiebreak as a single u64 max.
//
// R2/R3 lesson: launch_bounds(1024,4) only CAPS VGPRs (min waves/EU); the
// backend still targeted 8 waves/EU -> 48 VGPRs -> spilled the point arrays
// to scratch and re-streamed them every one of the 255 iterations.
// amdgpu_waves_per_eu(4,4) pins the occupancy target itself: budget = 128
// VGPR, allocator keeps px/py/pz/dist (64 regs) truly resident.
__global__ __launch_bounds__(FPS_T)
__attribute__((amdgpu_waves_per_eu(4, 4)))
void fps_kernel(const float* __restrict__ p, int* __restrict__ idx_out)
{
    const int b = blockIdx.x;
    const int t = threadIdx.x;
    const int lane = t & 63;
    const float* pb = p + (size_t)b * NN * 3;

    float px[PPT], py[PPT], pz[PPT], dist[PPT];
#pragma unroll
    for (int k = 0; k < PPT; ++k) {
        const int n = t + k * FPS_T;
        px[k] = pb[n * 3 + 0];
        py[k] = pb[n * 3 + 1];
        pz[k] = pb[n * 3 + 2];
        dist[k] = 1e10f;
    }
    // Opaque to remat: loads must stay hoisted above the i-loop.
#pragma unroll
    for (int k = 0; k < PPT; ++k) {
        asm volatile("" : "+v"(px[k]), "+v"(py[k]), "+v"(pz[k]));
    }

    // double-buffered wave candidates -> one barrier per iteration
    __shared__ unsigned long long s_key[2][16];

    // current center in registers on every thread
    float cx = pb[0], cy = pb[1], cz = pb[2];
    if (t == 0) idx_out[b * MM + 0] = 0;

    for (int i = 1; i < MM; ++i) {
        float bv = -1.0f;
#pragma unroll
        for (int k = 0; k < PPT; ++k) {
            // exact numpy order: ((dx*dx + dy*dy) + dz*dz)
            const float dx = __fsub_rn(px[k], cx);
            const float dy = __fsub_rn(py[k], cy);
            const float dz = __fsub_rn(pz[k], cz);
            const float d = __fadd_rn(
                __fadd_rn(__fmul_rn(dx, dx), __fmul_rn(dy, dy)),
                __fmul_rn(dz, dz));
            const float nd = fminf(dist[k], d);
            dist[k] = nd;
            bv = fmaxf(bv, nd);
        }
        // post-pass argmax: descending k, == match -> smallest k wins,
        // identical selection to an in-loop strict-> scan.
        int bn = 0;
#pragma unroll
        for (int k = PPT - 1; k >= 0; --k) {
            if (dist[k] == bv) bn = t + k * FPS_T;
        }
        unsigned long long key =
            ((unsigned long long)__float_as_uint(bv) << 32) |
            (unsigned int)(~bn);
        // 64-lane butterfly: every lane ends with the wave max key
#pragma unroll
        for (int off = 32; off > 0; off >>= 1) {
            const unsigned long long ok = __shfl_xor(key, off);
            if (ok > key) key = ok;
        }
        const int buf = i & 1;
        if (lane == 0) s_key[buf][t >> 6] = key;
        __syncthreads();
        // cross-wave reduce, lane-parallel: each 16-lane group loads all 16
        // wave keys (1 ds_read) and butterflies to the block max.
        unsigned long long fk = s_key[buf][lane & 15];
#pragma unroll
        for (int off = 8; off > 0; off >>= 1) {
            const unsigned long long ok = __shfl_xor(fk, off);
            if (ok > fk) fk = ok;
        }
        const int fn = __builtin_amdgcn_readfirstlane(~((unsigned int)fk));
        // scalar-uniform broadcast load of the new center (L1/L2-resident)
        cx = pb[fn * 3 + 0];
        cy = pb[fn * 3 + 1];
        cz = pb[fn * 3 + 2];
        if (t == 0) idx_out[b * MM + i] = fn;
        // no second barrier: next iter writes s_key[buf^1]; writes to
        // s_key[buf] recur only after the NEXT barrier, which orders them
        // after every wave's reads above.
    }
}

// ---------------- Ball query: one wave per center, 128 pts/iter -------------
__global__ __launch_bounds__(64) void ballq_kernel(
    const float* __restrict__ p, const int* __restrict__ idx,
    int* __restrict__ nidx, float* __restrict__ grouped_p,
    float* __restrict__ center_p)
{
    const int bm = blockIdx.x;
    const int b = bm >> 8;
    const int m = bm & 255;
    const int lane = threadIdx.x;
    const float* pb = p + (size_t)b * NN * 3;

    const int cidx = idx[bm];
    const float cx = pb[cidx * 3 + 0];
    const float cy = pb[cidx * 3 + 1];
    const float cz = pb[cidx * 3 + 2];

    if (lane < 3) {
        center_p[bm * 3 + lane] = (lane == 0) ? cx : (lane == 1) ? cy : cz;
    }

    // r2 must be f32(0.01) == 0x3C23D70A; 0.1f*0.1f rounds one ULP higher.
    const float R2 = 0.01f;

    __shared__ int lidx[NS];

    int found = 0;
    for (int base = 0; base < NN && found < NS; base += 128) {
        const int n0 = base + lane;
        const int n1 = base + 64 + lane;
        const float dx0 = __fsub_rn(pb[n0 * 3 + 0], cx);
        const float dy0 = __fsub_rn(pb[n0 * 3 + 1], cy);
        const float dz0 = __fsub_rn(pb[n0 * 3 + 2], cz);
        const float d20 = __fadd_rn(
            __fadd_rn(__fmul_rn(dx0, dx0), __fmul_rn(dy0, dy0)),
            __fmul_rn(dz0, dz0));
        const float dx1 = __fsub_rn(pb[n1 * 3 + 0], cx);
        const float dy1 = __fsub_rn(pb[n1 * 3 + 1], cy);
        const float dz1 = __fsub_rn(pb[n1 * 3 + 2], cz);
        const float d21 = __fadd_rn(
            __fadd_rn(__fmul_rn(dx1, dx1), __fmul_rn(dy1, dy1)),
            __fmul_rn(dz1, dz1));
        const bool w0 = d20 < R2;
        const bool w1 = d21 < R2;
        const unsigned long long m0 = __ballot(w0);
        const unsigned long long m1 = __ballot(w1);
        const int pc0 = (int)__popcll(m0);
        const unsigned long long below = (1ull << lane) - 1ull;
        const int slot0 = found + __popcll(m0 & below);
        const int slot1 = found + pc0 + __popcll(m1 & below);
        if (w0 && slot0 < NS) lidx[slot0] = n0;
        if (w1 && slot1 < NS) lidx[slot1] = n1;
        found += pc0 + (int)__popcll(m1);
    }
    __syncthreads();

    const int nfound = found < NS ? found : NS;
    if (lane < NS) {
        const int s = lane;
        const int n = (s < nfound) ? lidx[s] : lidx[0];
        nidx[bm * NS + s] = n;
        const float gx = __fsub_rn(pb[n * 3 + 0], cx);
        const float gy = __fsub_rn(pb[n * 3 + 1], cy);
        const float gz = __fsub_rn(pb[n * 3 + 2], cz);
        grouped_p[(((size_t)b * 3 + 0) * MM + m) * NS + s] = gx;
        grouped_p[(((size_t)b * 3 + 1) * MM + m) * NS + s] = gy;
        grouped_p[(((size_t)b * 3 + 2) * MM + m) * NS + s] = gz;
    }
}

// ---------------- fj gather: one block per (b,m) ----------------------------
__global__ __launch_bounds__(256) void fj_kernel(
    const float* __restrict__ x, const int* __restrict__ nidx,
    float* __restrict__ fj)
{
    const int bm = blockIdx.x;
    const int b = bm >> 8;
    const int m = bm & 255;

    __shared__ int lidx[NS];
    if (threadIdx.x < NS) lidx[threadIdx.x] = nidx[bm * NS + threadIdx.x];
    __syncthreads();

    const int s  = threadIdx.x & 31;
    const int c0 = threadIdx.x >> 5;   // 0..7
    const int n = lidx[s];
    const float* xb = x + (size_t)b * CC * NN;
    float* ob = fj + (size_t)b * CC * MM * NS + (size_t)m * NS + s;

#pragma unroll
    for (int c = c0; c < CC; c += 8) {
        ob[(size_t)c * MM * NS] = xb[(size_t)c * NN + n];
    }
}

// ---------------- center_x gather: one block per (b,c) ----------------------
__global__ __launch_bounds__(256) void cx_kernel(
    const float* __restrict__ x, const int* __restrict__ idx,
    float* __restrict__ center_x)
{
    const int bc = blockIdx.x;
    const int b = bc >> 7;
    const int m = threadIdx.x;
    const int n = idx[b * MM + m];
    center_x[(size_t)bc * MM + m] = x[(size_t)bc * NN + n];
}

extern "C" void kernel_launch(void* const* d_in, const int* in_sizes, int n_in,
                              void* d_out, int out_size, void* d_ws, size_t ws_size,
                              hipStream_t stream) {
    const float* p = (const float*)d_in[0];   // [8,16384,3]
    const float* x = (const float*)d_in[1];   // [8,128,16384]
    float* out = (float*)d_out;

    float* grouped_p = out + OFF_GP;
    float* center_p  = out + OFF_CP;
    float* fj        = out + OFF_FJ;
    float* center_x  = out + OFF_CX;

    int* idx  = (int*)d_ws;                   // [8,256]
    int* nidx = idx + BB * MM;                // [8,256,32]

    fps_kernel<<<BB, FPS_T, 0, stream>>>(p, idx);
    ballq_kernel<<<BB * MM, 64, 0, stream>>>(p, idx, nidx, grouped_p, center_p);
    fj_kernel<<<BB * MM, 256, 0, stream>>>(x, nidx, fj);
    cx_kernel<<<BB * CC, 256, 0, stream>>>(x, idx, center_x);
}